// Round 4
// baseline (98.583 us; speedup 1.0000x reference)
//
#include <hip/hip_runtime.h>
#include <math.h>

// ConditionalInstanceNorm1D: x[B,C,L] fp32, weight[S,C], bias[S,C], style_ids[B] int
// out = (x - mean_row) * rsqrt(var_row + eps) * w[sid,c] + b[sid,c]
// 4 rows per block (consecutive, same sample b => same sid). Ping-pong register
// buffers: row r+1's NT loads fly across row r's reduce/barrier/store phase.
// Single HBM read + single HBM write total.

constexpr int L_LEN = 8192;
constexpr int NTHR  = 512;
constexpr int VPT   = L_LEN / (NTHR * 4);   // float4 loads per thread per row = 4
constexpr int NWAVE = NTHR / 64;            // 8 waves
constexpr int RPB   = 4;                    // rows per block
constexpr float EPS_ = 1e-5f;

typedef float f32x4 __attribute__((ext_vector_type(4)));

__global__ __launch_bounds__(NTHR) void cin1d_kernel(
    const float* __restrict__ x,
    const float* __restrict__ weight,
    const float* __restrict__ bias,
    const int*   __restrict__ style_ids,
    float* __restrict__ out,
    int C)
{
    const int row0 = blockIdx.x * RPB;
    const int b    = row0 / C;               // RPB divides C -> same b for all 4 rows
    const int c0   = row0 - b * C;
    const int t    = threadIdx.x;
    const int wave = t >> 6;
    const int lane = t & 63;

    // Per-block-uniform affine params (scalar path), hoisted.
    const int sid = style_ids[b];
    float w_[RPB], bb_[RPB];
#pragma unroll
    for (int r = 0; r < RPB; ++r) {
        w_[r]  = weight[sid * C + c0 + r];
        bb_[r] = bias[sid * C + c0 + r];
    }

    constexpr int ROWV = L_LEN / 4;          // f32x4 per row = 2048
    const f32x4* __restrict__ xr   = reinterpret_cast<const f32x4*>(x   + (size_t)row0 * L_LEN);
    f32x4* __restrict__       outr = reinterpret_cast<f32x4*>(out + (size_t)row0 * L_LEN);

    __shared__ float s_sum[RPB][NWAVE];
    __shared__ float s_sq[RPB][NWAVE];

    f32x4 buf[2][VPT];                       // static-indexed (loop fully unrolled)

    // Prefetch row 0.
#pragma unroll
    for (int i = 0; i < VPT; ++i)
        buf[0][i] = __builtin_nontemporal_load(&xr[t + i * NTHR]);

#pragma unroll
    for (int r = 0; r < RPB; ++r) {
        const int cur = r & 1;

        // Issue next row's loads first — they stay in flight across this row's
        // reduce + barrier + store (counted vmcnt, no full drain).
        if (r + 1 < RPB) {
#pragma unroll
            for (int i = 0; i < VPT; ++i)
                buf[cur ^ 1][i] = __builtin_nontemporal_load(&xr[(r + 1) * ROWV + t + i * NTHR]);
        }

        float sum = 0.f, sq = 0.f;
#pragma unroll
        for (int i = 0; i < VPT; ++i) {
            const f32x4 v = buf[cur][i];
            sum += v.x + v.y + v.z + v.w;
            sq  += v.x * v.x + v.y * v.y + v.z * v.z + v.w * v.w;
        }

#pragma unroll
        for (int off = 32; off > 0; off >>= 1) {
            sum += __shfl_xor(sum, off, 64);
            sq  += __shfl_xor(sq,  off, 64);
        }

        if (lane == 0) { s_sum[r][wave] = sum; s_sq[r][wave] = sq; }
        __syncthreads();

        float ts = 0.f, tq = 0.f;
#pragma unroll
        for (int wv = 0; wv < NWAVE; ++wv) { ts += s_sum[r][wv]; tq += s_sq[r][wv]; }
        const float inv_n = 1.0f / (float)L_LEN;
        const float mean  = ts * inv_n;
        const float var   = tq * inv_n - mean * mean;
        const float rstd  = rsqrtf(var + EPS_);
        const float scale = w_[r] * rstd;
        const float shift = bb_[r] - mean * scale;

#pragma unroll
        for (int i = 0; i < VPT; ++i) {
            const f32x4 v = buf[cur][i];
            f32x4 o;
            o.x = v.x * scale + shift;
            o.y = v.y * scale + shift;
            o.z = v.z * scale + shift;
            o.w = v.w * scale + shift;
            __builtin_nontemporal_store(o, &outr[r * ROWV + t + i * NTHR]);
        }
    }
}

extern "C" void kernel_launch(void* const* d_in, const int* in_sizes, int n_in,
                              void* d_out, int out_size, void* d_ws, size_t ws_size,
                              hipStream_t stream) {
    const float* x      = (const float*)d_in[0];
    const float* weight = (const float*)d_in[1];
    const float* bias   = (const float*)d_in[2];
    const int*   sids   = (const int*)d_in[3];
    float*       out    = (float*)d_out;

    const int B = in_sizes[3];                 // style_ids has B elements
    const int C = in_sizes[0] / (B * L_LEN);   // x = B*C*L
    const int rows = B * C;                    // 8192
    const int blocks = rows / RPB;             // 2048

    cin1d_kernel<<<blocks, NTHR, 0, stream>>>(x, weight, bias, sids, out, C);
}

// Round 5
// 95.667 us; speedup vs baseline: 1.0305x; 1.0305x over previous
//
#include <hip/hip_runtime.h>
#include <math.h>

// ConditionalInstanceNorm1D: x[B,C,L] fp32, weight[S,C], bias[S,C], style_ids[B] int
// out = (x - mean_row) * rsqrt(var_row + eps) * w[sid,c] + b[sid,c]
// One block per (b,c) row. L=8192. 256 threads, 32 floats/thread in registers.
// Single HBM read + single HBM write; NT hints; affine params hoisted; single
// barrier with redundant per-thread finalize. 8 blocks/CU for fine phase interleave.

constexpr int L_LEN  = 8192;
constexpr int NTHR   = 256;
constexpr int VPT    = L_LEN / (NTHR * 4);   // float4 loads per thread = 8
constexpr int NWAVE  = NTHR / 64;            // 4 waves
constexpr float EPS_ = 1e-5f;

typedef float f32x4 __attribute__((ext_vector_type(4)));

__global__ __launch_bounds__(NTHR) void cin1d_kernel(
    const float* __restrict__ x,
    const float* __restrict__ weight,
    const float* __restrict__ bias,
    const int*   __restrict__ style_ids,
    float* __restrict__ out,
    int C)
{
    const int row = blockIdx.x;          // row = b*C + c
    const int b   = row / C;
    const int c   = row - b * C;
    const int t   = threadIdx.x;

    // Hoisted affine-param chain (block-uniform scalar loads); latency hides
    // under the streaming loads below.
    const int   sid = style_ids[b];
    const float w   = weight[sid * C + c];
    const float bb  = bias[sid * C + c];

    const f32x4* __restrict__ xr   = reinterpret_cast<const f32x4*>(x + (size_t)row * L_LEN);
    f32x4* __restrict__       outr = reinterpret_cast<f32x4*>(out + (size_t)row * L_LEN);

    // Load row into registers (coalesced 16B, non-temporal), accumulate sum & sumsq.
    f32x4 v[VPT];
    float sum = 0.f, sq = 0.f;
#pragma unroll
    for (int i = 0; i < VPT; ++i) {
        v[i] = __builtin_nontemporal_load(&xr[t + i * NTHR]);
        sum += v[i].x + v[i].y + v[i].z + v[i].w;
        sq  += v[i].x * v[i].x + v[i].y * v[i].y + v[i].z * v[i].z + v[i].w * v[i].w;
    }

    // Wave(64) xor-butterfly: all lanes end with the wave total.
#pragma unroll
    for (int off = 32; off > 0; off >>= 1) {
        sum += __shfl_xor(sum, off, 64);
        sq  += __shfl_xor(sq,  off, 64);
    }

    __shared__ float s_sum[NWAVE];
    __shared__ float s_sq[NWAVE];
    const int wave = t >> 6;
    const int lane = t & 63;
    if (lane == 0) { s_sum[wave] = sum; s_sq[wave] = sq; }
    __syncthreads();

    // Redundant per-thread finalize (broadcast LDS reads) — no second barrier.
    float ts = 0.f, tq = 0.f;
#pragma unroll
    for (int wv = 0; wv < NWAVE; ++wv) { ts += s_sum[wv]; tq += s_sq[wv]; }
    const float inv_n = 1.0f / (float)L_LEN;
    const float mean  = ts * inv_n;
    const float var   = tq * inv_n - mean * mean;
    const float rstd  = rsqrtf(var + EPS_);
    const float scale = w * rstd;
    const float shift = bb - mean * scale;

#pragma unroll
    for (int i = 0; i < VPT; ++i) {
        f32x4 o;
        o.x = v[i].x * scale + shift;
        o.y = v[i].y * scale + shift;
        o.z = v[i].z * scale + shift;
        o.w = v[i].w * scale + shift;
        __builtin_nontemporal_store(o, &outr[t + i * NTHR]);
    }
}

extern "C" void kernel_launch(void* const* d_in, const int* in_sizes, int n_in,
                              void* d_out, int out_size, void* d_ws, size_t ws_size,
                              hipStream_t stream) {
    const float* x      = (const float*)d_in[0];
    const float* weight = (const float*)d_in[1];
    const float* bias   = (const float*)d_in[2];
    const int*   sids   = (const int*)d_in[3];
    float*       out    = (float*)d_out;

    const int B = in_sizes[3];                 // style_ids has B elements
    const int C = in_sizes[0] / (B * L_LEN);   // x = B*C*L
    const int rows = B * C;                    // 8192 blocks

    cin1d_kernel<<<rows, NTHR, 0, stream>>>(x, weight, bias, sids, out, C);
}